// Round 23
// baseline (70.977 us; speedup 1.0000x reference)
//
#include <hip/hip_runtime.h>
#include <math.h>

// Problem constants
#define QDIM 512     // 2^9 state dim
#define DD   128     // K*C_IN = input dim of quadratic form
#define LIN  4096
#define LOUT 4089    // (4096 - 7 - 1)/1 + 1
#define NC   16      // C_IN
#define NB   16      // batch

typedef __attribute__((ext_vector_type(8))) short bf16x8;
typedef __attribute__((ext_vector_type(4))) float f32x4;

// Scratch in device globals (NOT d_ws) — R5 lesson. Every element rewritten
// each call before read. R8+R11: no grid barriers. R19: Q-path (formq node
// buys 4x less quad MFMA). R18: cooperative LDS staging. R16: per-CU byte
// stream is the wall -> mm uses 2 rows/block (1 block/CU, W streamed once).
__device__ float  g_B[QDIM * DD];          // W1 / A (ping-pong) f32
__device__ float  g_C[QDIM * DD];          // W2 f32
__device__ unsigned short g_Qh[DD * DD];   // bf16 hi part of Q
__device__ unsigned short g_Ql[DD * DD];   // bf16 residual of Q

// ---- bf16 helpers (RNE) ----
__device__ __forceinline__ unsigned short f2bf(float f) {
  union { float f; unsigned u; } v; v.f = f;
  unsigned u = v.u + 0x7FFFu + ((v.u >> 16) & 1u);
  return (unsigned short)(u >> 16);
}
__device__ __forceinline__ float bf2f(unsigned short h) {
  union { unsigned u; float f; } v; v.u = ((unsigned)h) << 16;
  return v.f;
}

// ---------------------------------------------------------------------------
// Precompute. Row i of E*R*W = (R^T e_i)^T W (transposed butterflies,
// reverse qubit order, on the E-row in LDS).
// ---------------------------------------------------------------------------
__device__ __forceinline__ void butterfly_T(float* col, const float* theta,
                                            int l, int p) {
  #pragma unroll
  for (int qq = 0; qq < 9; ++qq) {
    int q = 8 - qq;                    // reverse order for transpose
    float half = theta[l * 9 + q] * 0.5f;
    float c = cosf(half), s = sinf(half);
    int right = QDIM >> (q + 1);
    int a = p >> (8 - q);
    int r = p & (right - 1);
    int i0 = (a * 2) * right + r;
    int i1 = i0 + right;
    float v0 = col[i0], v1 = col[i1];
    col[i0] = c * v0 + s * v1;         // transposed 2x2
    col[i1] = c * v1 - s * v0;
    __syncthreads();
  }
}

// W1[i][j] = (R1^T e_i)[j], j<128  -> g_B   (verbatim R20)
__global__ __launch_bounds__(256) void w1_kernel(const float* __restrict__ E,
                                                 const float* __restrict__ theta) {
  __shared__ float erow[QDIM];
  int i = blockIdx.x;
  int p = threadIdx.x;
  erow[p]       = E[i * QDIM + p];
  erow[p + 256] = E[i * QDIM + p + 256];
  __syncthreads();
  butterfly_T(erow, theta, 0, p);
  if (p < DD) g_B[i * DD + p] = erow[p];
}

// dst rows {2i, 2i+1} = (R_l^T e_row)^T * src.  256 blocks = 1 block/CU:
// W (256KB) streamed ONCE per CU (R20: 2 blocks/CU = 512KB/CU stream).
// Per-row accumulator/reduction order identical to R20 -> absmax canary.
__global__ __launch_bounds__(256) void mm_fused2_kernel(const float* __restrict__ E,
                                                        const float* __restrict__ theta,
                                                        int l, int sel) {
  const float* W = sel ? g_C : g_B;
  float* D       = sel ? g_B : g_C;
  __shared__ float er[2][QDIM];
  __shared__ float part[2][DD];
  int i0 = blockIdx.x * 2;
  int tid = threadIdx.x;
  #pragma unroll
  for (int rr = 0; rr < 2; ++rr) {
    er[rr][tid]       = E[(i0 + rr) * QDIM + tid];
    er[rr][tid + 256] = E[(i0 + rr) * QDIM + tid + 256];
  }
  __syncthreads();
  // transposed butterflies, both rows per barrier step
  #pragma unroll
  for (int qq = 0; qq < 9; ++qq) {
    int q = 8 - qq;
    float half = theta[l * 9 + q] * 0.5f;
    float c = cosf(half), s = sinf(half);
    int right = QDIM >> (q + 1);
    int a = tid >> (8 - q);
    int r = tid & (right - 1);
    int x0 = (a * 2) * right + r;
    int x1 = x0 + right;
    #pragma unroll
    for (int rr = 0; rr < 2; ++rr) {
      float v0 = er[rr][x0], v1 = er[rr][x1];
      er[rr][x0] = c * v0 + s * v1;
      er[rr][x1] = c * v1 - s * v0;
    }
    __syncthreads();
  }

  int j = tid & 127, h = tid >> 7;
  float a0[2] = {0.f, 0.f}, a1[2] = {0.f, 0.f};
  float a2[2] = {0.f, 0.f}, a3[2] = {0.f, 0.f};
  int m0 = h * 256;
  #pragma unroll 4
  for (int m = m0; m < m0 + 256; m += 4) {
    float w0 = W[(m + 0) * DD + j];
    float w1 = W[(m + 1) * DD + j];
    float w2 = W[(m + 2) * DD + j];
    float w3 = W[(m + 3) * DD + j];
    #pragma unroll
    for (int rr = 0; rr < 2; ++rr) {
      a0[rr] = fmaf(er[rr][m + 0], w0, a0[rr]);
      a1[rr] = fmaf(er[rr][m + 1], w1, a1[rr]);
      a2[rr] = fmaf(er[rr][m + 2], w2, a2[rr]);
      a3[rr] = fmaf(er[rr][m + 3], w3, a3[rr]);
    }
  }
  float sum[2];
  #pragma unroll
  for (int rr = 0; rr < 2; ++rr) sum[rr] = (a0[rr] + a1[rr]) + (a2[rr] + a3[rr]);
  if (h == 1) {
    #pragma unroll
    for (int rr = 0; rr < 2; ++rr) part[rr][j] = sum[rr];
  }
  __syncthreads();
  if (h == 0) {
    #pragma unroll
    for (int rr = 0; rr < 2; ++rr)
      D[(i0 + rr) * DD + j] = sum[rr] + part[rr][j];
  }
}

// Q[j1][j2] = sum_i sgn(i) A[i][j1] A[i][j2]; A = g_B. Emit bf16 hi/lo.
// (verbatim R20)
__global__ __launch_bounds__(256) void formq_kernel() {
  const float* A = g_B;
  __shared__ float colA[QDIM];
  __shared__ float part[DD];
  int j1 = blockIdx.x;
  int tid = threadIdx.x;
  int j2 = tid & 127, h = tid >> 7;
  for (int i = tid; i < QDIM; i += 256) {
    float sgn = (i < 256) ? 1.0f : -1.0f;
    colA[i] = sgn * A[i * DD + j1];
  }
  __syncthreads();
  float a0 = 0.f, a1 = 0.f, a2 = 0.f, a3 = 0.f;
  int i0 = h * 256;
  #pragma unroll 8
  for (int i = i0; i < i0 + 256; i += 4) {
    a0 = fmaf(colA[i + 0], A[(i + 0) * DD + j2], a0);
    a1 = fmaf(colA[i + 1], A[(i + 1) * DD + j2], a1);
    a2 = fmaf(colA[i + 2], A[(i + 2) * DD + j2], a2);
    a3 = fmaf(colA[i + 3], A[(i + 3) * DD + j2], a3);
  }
  float sum = (a0 + a1) + (a2 + a3);
  if (h == 1) part[j2] = sum;
  __syncthreads();
  if (h == 0) {
    sum += part[j2];
    unsigned short hi = f2bf(sum);
    unsigned short lo = f2bf(sum - bf2f(hi));
    g_Qh[j1 * DD + j2] = hi;
    g_Ql[j1 * DD + j2] = lo;
  }
}

// ---------------------------------------------------------------------------
// quadQ (verbatim R20, measured-good): Qh staged in LDS (32KB, swizzled),
// Ql streamed from L2; 64-t tiles, 1024 blocks, 4/CU.
// ---------------------------------------------------------------------------
__global__ __launch_bounds__(256, 4) void quadQ_kernel(const float* __restrict__ x,
                                                       float* __restrict__ out) {
  __shared__ float xs[NC][72];                 // 71 used (64 t + 7 halo)
  __shared__ unsigned short sh_full[DD * DD];  // Qh, 32 KB, swizzled
  int b = blockIdx.x;
  int t0 = blockIdx.y * 64;
  int tid = threadIdx.x;
  int lane = tid & 63;
  int w = tid >> 6;                            // wave: t-rows [w*16, w*16+16)
  const float* xb = x + (size_t)b * NC * LIN;

  for (int idx = tid; idx < NC * 71; idx += 256) {
    int c = idx / 71, o = idx % 71;
    int g = t0 + o;
    xs[c][o] = (g < LIN) ? xb[c * LIN + g] : 0.0f;
  }
  // stage Qh (2048 granules of 8 u16), XOR swizzle: u16col ^= (row&7)<<3
  #pragma unroll
  for (int it = 0; it < 8; ++it) {
    int flat = it * 256 + tid;
    int row = flat >> 4;                       // 0..127
    int g8 = flat & 15;
    int lidx = row * DD + ((g8 * 8) ^ ((row & 7) << 3));
    *(bf16x8*)&sh_full[lidx] = *(const bf16x8*)(g_Qh + row * DD + g8 * 8);
  }
  __syncthreads();

  int lrow = lane & 15;
  int lgrp = lane >> 4;

  f32x4 acc[8];
  #pragma unroll
  for (int n = 0; n < 8; ++n) acc[n] = (f32x4){0.f, 0.f, 0.f, 0.f};

  #pragma unroll
  for (int kb = 0; kb < 4; ++kb) {
    int c = kb * 4 + lgrp;
    int tl = w * 16 + lrow;
    bf16x8 a_hi, a_lo;
    #pragma unroll
    for (int e = 0; e < 8; ++e) {
      float v = xs[c][tl + e];
      unsigned short hh = f2bf(v);
      unsigned short ll = f2bf(v - bf2f(hh));
      a_hi[e] = (short)hh;
      a_lo[e] = (short)ll;
    }
    #pragma unroll
    for (int n = 0; n < 8; ++n) {
      int row = n * 16 + lrow;
      int col = kb * 32 + lgrp * 8;
      bf16x8 b_hi = *(const bf16x8*)&sh_full[row * DD + (col ^ ((row & 7) << 3))];
      bf16x8 b_lo = *(const bf16x8*)(g_Ql + row * DD + col);
      acc[n] = __builtin_amdgcn_mfma_f32_16x16x32_bf16(a_hi, b_hi, acc[n], 0, 0, 0);
      acc[n] = __builtin_amdgcn_mfma_f32_16x16x32_bf16(a_hi, b_lo, acc[n], 0, 0, 0);
      acc[n] = __builtin_amdgcn_mfma_f32_16x16x32_bf16(a_lo, b_hi, acc[n], 0, 0, 0);
    }
  }

  // Epilogue: dot with v and ||v||^2, 16-lane reduce.
  float pd[4] = {0.f, 0.f, 0.f, 0.f};
  float pn[4] = {0.f, 0.f, 0.f, 0.f};
  #pragma unroll
  for (int n = 0; n < 8; ++n) {
    int i = n * 16 + lrow;
    int cc = i >> 3, ko = i & 7;
    #pragma unroll
    for (int r = 0; r < 4; ++r) {
      int tl = w * 16 + lgrp * 4 + r;
      float v = xs[cc][tl + ko];
      pd[r] = fmaf(acc[n][r], v, pd[r]);
      pn[r] = fmaf(v, v, pn[r]);
    }
  }
  #pragma unroll
  for (int r = 0; r < 4; ++r) {
    #pragma unroll
    for (int m = 1; m < 16; m <<= 1) {
      pd[r] += __shfl_xor(pd[r], m);
      pn[r] += __shfl_xor(pn[r], m);
    }
  }
  if (lrow == 0) {
    #pragma unroll
    for (int r = 0; r < 4; ++r) {
      int t = t0 + w * 16 + lgrp * 4 + r;
      if (t < LOUT) out[(size_t)b * LOUT + t] = pd[r] / (pn[r] + 1e-12f);
    }
  }
}

// ---------------------------------------------------------------------------

extern "C" void kernel_launch(void* const* d_in, const int* in_sizes, int n_in,
                              void* d_out, int out_size, void* d_ws, size_t ws_size,
                              hipStream_t stream) {
  const float* x     = (const float*)d_in[0];   // (16,16,4096) f32
  const float* E     = (const float*)d_in[1];   // (512,512)    f32
  const float* theta = (const float*)d_in[2];   // (3,9)        f32
  float* out = (float*)d_out;                   // (16,1,1,4089) f32
  (void)d_ws; (void)ws_size;

  w1_kernel<<<QDIM, 256, 0, stream>>>(E, theta);                // -> g_B (W1)
  mm_fused2_kernel<<<QDIM / 2, 256, 0, stream>>>(E, theta, 1, 0); // g_B -> g_C
  mm_fused2_kernel<<<QDIM / 2, 256, 0, stream>>>(E, theta, 2, 1); // g_C -> g_B (A)
  formq_kernel<<<DD, 256, 0, stream>>>();                       // g_B -> g_Qh/g_Ql
  quadQ_kernel<<<dim3(NB, 64), 256, 0, stream>>>(x, out);
}

// Round 24
// 54.878 us; speedup vs baseline: 1.2934x; 1.2934x over previous
//
#include <hip/hip_runtime.h>
#include <math.h>

// Problem constants
#define QDIM 512     // 2^9 state dim
#define DD   128     // K*C_IN = input dim of quadratic form
#define LIN  4096
#define LOUT 4089    // (4096 - 7 - 1)/1 + 1
#define NC   16      // C_IN
#define NB   16      // batch

typedef __attribute__((ext_vector_type(8))) short bf16x8;
typedef __attribute__((ext_vector_type(4))) float f32x4;

// Scratch in device globals (NOT d_ws) — R5 lesson. Every element rewritten
// each call before read. R8+R11: no grid barriers. R19: Q-path. R18:
// cooperative LDS staging. R23: mm is LATENCY-bound, not byte-bound
// (1 blk/CU regressed) -> raise TLP at same per-block bytes (split-K x4).
__device__ float  g_B[QDIM * DD];          // W1 / A (ping-pong) f32
__device__ float  g_C[QDIM * DD];          // W2 f32
__device__ unsigned short g_Qh[DD * DD];   // bf16 hi part of Q
__device__ unsigned short g_Ql[DD * DD];   // bf16 residual of Q

// ---- bf16 helpers (RNE) ----
__device__ __forceinline__ unsigned short f2bf(float f) {
  union { float f; unsigned u; } v; v.f = f;
  unsigned u = v.u + 0x7FFFu + ((v.u >> 16) & 1u);
  return (unsigned short)(u >> 16);
}
__device__ __forceinline__ float bf2f(unsigned short h) {
  union { unsigned u; float f; } v; v.u = ((unsigned)h) << 16;
  return v.f;
}

// ---------------------------------------------------------------------------
// Precompute. Row i of E*R*W = (R^T e_i)^T W (transposed butterflies,
// reverse qubit order, on the E-row in LDS).
// ---------------------------------------------------------------------------
__device__ __forceinline__ void butterfly_T(float* col, const float* theta,
                                            int l, int p) {
  #pragma unroll
  for (int qq = 0; qq < 9; ++qq) {
    int q = 8 - qq;                    // reverse order for transpose
    float half = theta[l * 9 + q] * 0.5f;
    float c = cosf(half), s = sinf(half);
    int right = QDIM >> (q + 1);
    int a = p >> (8 - q);
    int r = p & (right - 1);
    int i0 = (a * 2) * right + r;
    int i1 = i0 + right;
    float v0 = col[i0], v1 = col[i1];
    col[i0] = c * v0 + s * v1;         // transposed 2x2
    col[i1] = c * v1 - s * v0;
    __syncthreads();
  }
}

// W1[i][j] = (R1^T e_i)[j], j<128  -> g_B   (verbatim R20)
__global__ __launch_bounds__(256) void w1_kernel(const float* __restrict__ E,
                                                 const float* __restrict__ theta) {
  __shared__ float erow[QDIM];
  int i = blockIdx.x;
  int p = threadIdx.x;
  erow[p]       = E[i * QDIM + p];
  erow[p + 256] = E[i * QDIM + p + 256];
  __syncthreads();
  butterfly_T(erow, theta, 0, p);
  if (p < DD) g_B[i * DD + p] = erow[p];
}

// dst[i][:] = (R_l^T e_i)^T * src.  1 row/block, 512 blocks (R20 geometry —
// R23 proved fewer blocks regress), but 512 threads = 4 K-quarters ->
// 4 waves/SIMD (2x R20's TLP). sel: 0 = g_B->g_C, 1 = g_C->g_B.
__global__ __launch_bounds__(512) void mm_fused4_kernel(const float* __restrict__ E,
                                                        const float* __restrict__ theta,
                                                        int l, int sel) {
  const float* W = sel ? g_C : g_B;
  float* D       = sel ? g_B : g_C;
  __shared__ float erow[QDIM];
  __shared__ float part[4][DD];
  int i = blockIdx.x;
  int tid = threadIdx.x;                 // 0..511
  erow[tid] = E[i * QDIM + tid];
  __syncthreads();
  // transposed butterflies: 256 worker threads, barriers outside the guard
  #pragma unroll
  for (int qq = 0; qq < 9; ++qq) {
    int q = 8 - qq;
    float half = theta[l * 9 + q] * 0.5f;
    float c = cosf(half), s = sinf(half);
    if (tid < 256) {
      int right = QDIM >> (q + 1);
      int a = tid >> (8 - q);
      int r = tid & (right - 1);
      int x0 = (a * 2) * right + r;
      int x1 = x0 + right;
      float v0 = erow[x0], v1 = erow[x1];
      erow[x0] = c * v0 + s * v1;
      erow[x1] = c * v1 - s * v0;
    }
    __syncthreads();
  }

  int j = tid & 127, qtr = tid >> 7;     // 128 j x 4 K-quarters
  float a0 = 0.f, a1 = 0.f, a2 = 0.f, a3 = 0.f;
  int m0 = qtr * 128;
  #pragma unroll 8
  for (int m = m0; m < m0 + 128; m += 4) {
    a0 = fmaf(erow[m + 0], W[(m + 0) * DD + j], a0);
    a1 = fmaf(erow[m + 1], W[(m + 1) * DD + j], a1);
    a2 = fmaf(erow[m + 2], W[(m + 2) * DD + j], a2);
    a3 = fmaf(erow[m + 3], W[(m + 3) * DD + j], a3);
  }
  part[qtr][j] = (a0 + a1) + (a2 + a3);
  __syncthreads();
  if (tid < DD) {
    D[i * DD + tid] = (part[0][tid] + part[1][tid]) +
                      (part[2][tid] + part[3][tid]);
  }
}

// Q[j1][j2] = sum_i sgn(i) A[i][j1] A[i][j2]; A = g_B. Emit bf16 hi/lo.
// (verbatim R20)
__global__ __launch_bounds__(256) void formq_kernel() {
  const float* A = g_B;
  __shared__ float colA[QDIM];
  __shared__ float part[DD];
  int j1 = blockIdx.x;
  int tid = threadIdx.x;
  int j2 = tid & 127, h = tid >> 7;
  for (int i = tid; i < QDIM; i += 256) {
    float sgn = (i < 256) ? 1.0f : -1.0f;
    colA[i] = sgn * A[i * DD + j1];
  }
  __syncthreads();
  float a0 = 0.f, a1 = 0.f, a2 = 0.f, a3 = 0.f;
  int i0 = h * 256;
  #pragma unroll 8
  for (int i = i0; i < i0 + 256; i += 4) {
    a0 = fmaf(colA[i + 0], A[(i + 0) * DD + j2], a0);
    a1 = fmaf(colA[i + 1], A[(i + 1) * DD + j2], a1);
    a2 = fmaf(colA[i + 2], A[(i + 2) * DD + j2], a2);
    a3 = fmaf(colA[i + 3], A[(i + 3) * DD + j2], a3);
  }
  float sum = (a0 + a1) + (a2 + a3);
  if (h == 1) part[j2] = sum;
  __syncthreads();
  if (h == 0) {
    sum += part[j2];
    unsigned short hi = f2bf(sum);
    unsigned short lo = f2bf(sum - bf2f(hi));
    g_Qh[j1 * DD + j2] = hi;
    g_Ql[j1 * DD + j2] = lo;
  }
}

// ---------------------------------------------------------------------------
// quadQ (verbatim R20, measured-good): Qh staged in LDS (32KB, swizzled),
// Ql streamed from L2; 64-t tiles, 1024 blocks, 4/CU.
// ---------------------------------------------------------------------------
__global__ __launch_bounds__(256, 4) void quadQ_kernel(const float* __restrict__ x,
                                                       float* __restrict__ out) {
  __shared__ float xs[NC][72];                 // 71 used (64 t + 7 halo)
  __shared__ unsigned short sh_full[DD * DD];  // Qh, 32 KB, swizzled
  int b = blockIdx.x;
  int t0 = blockIdx.y * 64;
  int tid = threadIdx.x;
  int lane = tid & 63;
  int w = tid >> 6;                            // wave: t-rows [w*16, w*16+16)
  const float* xb = x + (size_t)b * NC * LIN;

  for (int idx = tid; idx < NC * 71; idx += 256) {
    int c = idx / 71, o = idx % 71;
    int g = t0 + o;
    xs[c][o] = (g < LIN) ? xb[c * LIN + g] : 0.0f;
  }
  // stage Qh (2048 granules of 8 u16), XOR swizzle: u16col ^= (row&7)<<3
  #pragma unroll
  for (int it = 0; it < 8; ++it) {
    int flat = it * 256 + tid;
    int row = flat >> 4;                       // 0..127
    int g8 = flat & 15;
    int lidx = row * DD + ((g8 * 8) ^ ((row & 7) << 3));
    *(bf16x8*)&sh_full[lidx] = *(const bf16x8*)(g_Qh + row * DD + g8 * 8);
  }
  __syncthreads();

  int lrow = lane & 15;
  int lgrp = lane >> 4;

  f32x4 acc[8];
  #pragma unroll
  for (int n = 0; n < 8; ++n) acc[n] = (f32x4){0.f, 0.f, 0.f, 0.f};

  #pragma unroll
  for (int kb = 0; kb < 4; ++kb) {
    int c = kb * 4 + lgrp;
    int tl = w * 16 + lrow;
    bf16x8 a_hi, a_lo;
    #pragma unroll
    for (int e = 0; e < 8; ++e) {
      float v = xs[c][tl + e];
      unsigned short hh = f2bf(v);
      unsigned short ll = f2bf(v - bf2f(hh));
      a_hi[e] = (short)hh;
      a_lo[e] = (short)ll;
    }
    #pragma unroll
    for (int n = 0; n < 8; ++n) {
      int row = n * 16 + lrow;
      int col = kb * 32 + lgrp * 8;
      bf16x8 b_hi = *(const bf16x8*)&sh_full[row * DD + (col ^ ((row & 7) << 3))];
      bf16x8 b_lo = *(const bf16x8*)(g_Ql + row * DD + col);
      acc[n] = __builtin_amdgcn_mfma_f32_16x16x32_bf16(a_hi, b_hi, acc[n], 0, 0, 0);
      acc[n] = __builtin_amdgcn_mfma_f32_16x16x32_bf16(a_hi, b_lo, acc[n], 0, 0, 0);
      acc[n] = __builtin_amdgcn_mfma_f32_16x16x32_bf16(a_lo, b_hi, acc[n], 0, 0, 0);
    }
  }

  // Epilogue: dot with v and ||v||^2, 16-lane reduce.
  float pd[4] = {0.f, 0.f, 0.f, 0.f};
  float pn[4] = {0.f, 0.f, 0.f, 0.f};
  #pragma unroll
  for (int n = 0; n < 8; ++n) {
    int i = n * 16 + lrow;
    int cc = i >> 3, ko = i & 7;
    #pragma unroll
    for (int r = 0; r < 4; ++r) {
      int tl = w * 16 + lgrp * 4 + r;
      float v = xs[cc][tl + ko];
      pd[r] = fmaf(acc[n][r], v, pd[r]);
      pn[r] = fmaf(v, v, pn[r]);
    }
  }
  #pragma unroll
  for (int r = 0; r < 4; ++r) {
    #pragma unroll
    for (int m = 1; m < 16; m <<= 1) {
      pd[r] += __shfl_xor(pd[r], m);
      pn[r] += __shfl_xor(pn[r], m);
    }
  }
  if (lrow == 0) {
    #pragma unroll
    for (int r = 0; r < 4; ++r) {
      int t = t0 + w * 16 + lgrp * 4 + r;
      if (t < LOUT) out[(size_t)b * LOUT + t] = pd[r] / (pn[r] + 1e-12f);
    }
  }
}

// ---------------------------------------------------------------------------

extern "C" void kernel_launch(void* const* d_in, const int* in_sizes, int n_in,
                              void* d_out, int out_size, void* d_ws, size_t ws_size,
                              hipStream_t stream) {
  const float* x     = (const float*)d_in[0];   // (16,16,4096) f32
  const float* E     = (const float*)d_in[1];   // (512,512)    f32
  const float* theta = (const float*)d_in[2];   // (3,9)        f32
  float* out = (float*)d_out;                   // (16,1,1,4089) f32
  (void)d_ws; (void)ws_size;

  w1_kernel<<<QDIM, 256, 0, stream>>>(E, theta);                 // -> g_B (W1)
  mm_fused4_kernel<<<QDIM, 512, 0, stream>>>(E, theta, 1, 0);    // g_B -> g_C
  mm_fused4_kernel<<<QDIM, 512, 0, stream>>>(E, theta, 2, 1);    // g_C -> g_B (A)
  formq_kernel<<<DD, 256, 0, stream>>>();                        // g_B -> g_Qh/g_Ql
  quadQ_kernel<<<dim3(NB, 64), 256, 0, stream>>>(x, out);
}

// Round 25
// 52.805 us; speedup vs baseline: 1.3442x; 1.0393x over previous
//
#include <hip/hip_runtime.h>
#include <math.h>

// Problem constants
#define QDIM 512     // 2^9 state dim
#define DD   128     // K*C_IN = input dim of quadratic form
#define LIN  4096
#define LOUT 4089    // (4096 - 7 - 1)/1 + 1
#define NC   16      // C_IN
#define NB   16      // batch

typedef __attribute__((ext_vector_type(8))) short bf16x8;
typedef __attribute__((ext_vector_type(4))) float f32x4;

// Scratch in device globals (NOT d_ws) — R5 lesson. Every element rewritten
// each call before read. R8+R11: no grid barriers. R19: Q-path. R18:
// cooperative LDS staging. R23/R24: small-matvec kernels are LATENCY-bound
// -> raise TLP via split-K at fixed per-block bytes (mm x4 = -7us; now formq).
__device__ float  g_B[QDIM * DD];          // W1 / A (ping-pong) f32
__device__ float  g_C[QDIM * DD];          // W2 f32
__device__ unsigned short g_Qh[DD * DD];   // bf16 hi part of Q
__device__ unsigned short g_Ql[DD * DD];   // bf16 residual of Q

// ---- bf16 helpers (RNE) ----
__device__ __forceinline__ unsigned short f2bf(float f) {
  union { float f; unsigned u; } v; v.f = f;
  unsigned u = v.u + 0x7FFFu + ((v.u >> 16) & 1u);
  return (unsigned short)(u >> 16);
}
__device__ __forceinline__ float bf2f(unsigned short h) {
  union { unsigned u; float f; } v; v.u = ((unsigned)h) << 16;
  return v.f;
}

// ---------------------------------------------------------------------------
// Precompute. Row i of E*R*W = (R^T e_i)^T W (transposed butterflies,
// reverse qubit order, on the E-row in LDS).
// ---------------------------------------------------------------------------
__device__ __forceinline__ void butterfly_T(float* col, const float* theta,
                                            int l, int p) {
  #pragma unroll
  for (int qq = 0; qq < 9; ++qq) {
    int q = 8 - qq;                    // reverse order for transpose
    float half = theta[l * 9 + q] * 0.5f;
    float c = cosf(half), s = sinf(half);
    int right = QDIM >> (q + 1);
    int a = p >> (8 - q);
    int r = p & (right - 1);
    int i0 = (a * 2) * right + r;
    int i1 = i0 + right;
    float v0 = col[i0], v1 = col[i1];
    col[i0] = c * v0 + s * v1;         // transposed 2x2
    col[i1] = c * v1 - s * v0;
    __syncthreads();
  }
}

// W1[i][j] = (R1^T e_i)[j], j<128  -> g_B   (verbatim R20/R24)
__global__ __launch_bounds__(256) void w1_kernel(const float* __restrict__ E,
                                                 const float* __restrict__ theta) {
  __shared__ float erow[QDIM];
  int i = blockIdx.x;
  int p = threadIdx.x;
  erow[p]       = E[i * QDIM + p];
  erow[p + 256] = E[i * QDIM + p + 256];
  __syncthreads();
  butterfly_T(erow, theta, 0, p);
  if (p < DD) g_B[i * DD + p] = erow[p];
}

// dst[i][:] = (R_l^T e_i)^T * src.  512 blocks x 512 threads (4 K-quarters)
// -> 4 waves/SIMD (verbatim R24, measured-good: -7us vs 2-half version).
__global__ __launch_bounds__(512) void mm_fused4_kernel(const float* __restrict__ E,
                                                        const float* __restrict__ theta,
                                                        int l, int sel) {
  const float* W = sel ? g_C : g_B;
  float* D       = sel ? g_B : g_C;
  __shared__ float erow[QDIM];
  __shared__ float part[4][DD];
  int i = blockIdx.x;
  int tid = threadIdx.x;                 // 0..511
  erow[tid] = E[i * QDIM + tid];
  __syncthreads();
  // transposed butterflies: 256 worker threads, barriers outside the guard
  #pragma unroll
  for (int qq = 0; qq < 9; ++qq) {
    int q = 8 - qq;
    float half = theta[l * 9 + q] * 0.5f;
    float c = cosf(half), s = sinf(half);
    if (tid < 256) {
      int right = QDIM >> (q + 1);
      int a = tid >> (8 - q);
      int r = tid & (right - 1);
      int x0 = (a * 2) * right + r;
      int x1 = x0 + right;
      float v0 = erow[x0], v1 = erow[x1];
      erow[x0] = c * v0 + s * v1;
      erow[x1] = c * v1 - s * v0;
    }
    __syncthreads();
  }

  int j = tid & 127, qtr = tid >> 7;     // 128 j x 4 K-quarters
  float a0 = 0.f, a1 = 0.f, a2 = 0.f, a3 = 0.f;
  int m0 = qtr * 128;
  #pragma unroll 8
  for (int m = m0; m < m0 + 128; m += 4) {
    a0 = fmaf(erow[m + 0], W[(m + 0) * DD + j], a0);
    a1 = fmaf(erow[m + 1], W[(m + 1) * DD + j], a1);
    a2 = fmaf(erow[m + 2], W[(m + 2) * DD + j], a2);
    a3 = fmaf(erow[m + 3], W[(m + 3) * DD + j], a3);
  }
  part[qtr][j] = (a0 + a1) + (a2 + a3);
  __syncthreads();
  if (tid < DD) {
    D[i * DD + tid] = (part[0][tid] + part[1][tid]) +
                      (part[2][tid] + part[3][tid]);
  }
}

// Q[j1][j2] = sum_i sgn(i) A[i][j1] A[i][j2]; A = g_B. Emit bf16 hi/lo.
// R25 change: 512 threads, split-K x4 (i-quarters of 128) -> 2x TLP on the
// active CUs (was 256 thr / 2 halves, latency-bound like pre-R24 mm).
__global__ __launch_bounds__(512) void formq_kernel() {
  const float* A = g_B;
  __shared__ float colA[QDIM];
  __shared__ float part[4][DD];
  int j1 = blockIdx.x;
  int tid = threadIdx.x;                 // 0..511
  int j2 = tid & 127, qtr = tid >> 7;    // 128 j2 x 4 i-quarters
  {
    float sgn = (tid < 256) ? 1.0f : -1.0f;
    colA[tid] = sgn * A[tid * DD + j1];
  }
  __syncthreads();
  float a0 = 0.f, a1 = 0.f, a2 = 0.f, a3 = 0.f;
  int i0 = qtr * 128;
  #pragma unroll 8
  for (int i = i0; i < i0 + 128; i += 4) {
    a0 = fmaf(colA[i + 0], A[(i + 0) * DD + j2], a0);
    a1 = fmaf(colA[i + 1], A[(i + 1) * DD + j2], a1);
    a2 = fmaf(colA[i + 2], A[(i + 2) * DD + j2], a2);
    a3 = fmaf(colA[i + 3], A[(i + 3) * DD + j2], a3);
  }
  part[qtr][j2] = (a0 + a1) + (a2 + a3);
  __syncthreads();
  if (tid < DD) {
    float sum = (part[0][tid] + part[1][tid]) +
                (part[2][tid] + part[3][tid]);
    unsigned short hi = f2bf(sum);
    unsigned short lo = f2bf(sum - bf2f(hi));
    g_Qh[j1 * DD + tid] = hi;
    g_Ql[j1 * DD + tid] = lo;
  }
}

// ---------------------------------------------------------------------------
// quadQ (verbatim R20/R24, measured-good): Qh staged in LDS (32KB, swizzled),
// Ql streamed from L2; 64-t tiles, 1024 blocks, 4/CU.
// ---------------------------------------------------------------------------
__global__ __launch_bounds__(256, 4) void quadQ_kernel(const float* __restrict__ x,
                                                       float* __restrict__ out) {
  __shared__ float xs[NC][72];                 // 71 used (64 t + 7 halo)
  __shared__ unsigned short sh_full[DD * DD];  // Qh, 32 KB, swizzled
  int b = blockIdx.x;
  int t0 = blockIdx.y * 64;
  int tid = threadIdx.x;
  int lane = tid & 63;
  int w = tid >> 6;                            // wave: t-rows [w*16, w*16+16)
  const float* xb = x + (size_t)b * NC * LIN;

  for (int idx = tid; idx < NC * 71; idx += 256) {
    int c = idx / 71, o = idx % 71;
    int g = t0 + o;
    xs[c][o] = (g < LIN) ? xb[c * LIN + g] : 0.0f;
  }
  // stage Qh (2048 granules of 8 u16), XOR swizzle: u16col ^= (row&7)<<3
  #pragma unroll
  for (int it = 0; it < 8; ++it) {
    int flat = it * 256 + tid;
    int row = flat >> 4;                       // 0..127
    int g8 = flat & 15;
    int lidx = row * DD + ((g8 * 8) ^ ((row & 7) << 3));
    *(bf16x8*)&sh_full[lidx] = *(const bf16x8*)(g_Qh + row * DD + g8 * 8);
  }
  __syncthreads();

  int lrow = lane & 15;
  int lgrp = lane >> 4;

  f32x4 acc[8];
  #pragma unroll
  for (int n = 0; n < 8; ++n) acc[n] = (f32x4){0.f, 0.f, 0.f, 0.f};

  #pragma unroll
  for (int kb = 0; kb < 4; ++kb) {
    int c = kb * 4 + lgrp;
    int tl = w * 16 + lrow;
    bf16x8 a_hi, a_lo;
    #pragma unroll
    for (int e = 0; e < 8; ++e) {
      float v = xs[c][tl + e];
      unsigned short hh = f2bf(v);
      unsigned short ll = f2bf(v - bf2f(hh));
      a_hi[e] = (short)hh;
      a_lo[e] = (short)ll;
    }
    #pragma unroll
    for (int n = 0; n < 8; ++n) {
      int row = n * 16 + lrow;
      int col = kb * 32 + lgrp * 8;
      bf16x8 b_hi = *(const bf16x8*)&sh_full[row * DD + (col ^ ((row & 7) << 3))];
      bf16x8 b_lo = *(const bf16x8*)(g_Ql + row * DD + col);
      acc[n] = __builtin_amdgcn_mfma_f32_16x16x32_bf16(a_hi, b_hi, acc[n], 0, 0, 0);
      acc[n] = __builtin_amdgcn_mfma_f32_16x16x32_bf16(a_hi, b_lo, acc[n], 0, 0, 0);
      acc[n] = __builtin_amdgcn_mfma_f32_16x16x32_bf16(a_lo, b_hi, acc[n], 0, 0, 0);
    }
  }

  // Epilogue: dot with v and ||v||^2, 16-lane reduce.
  float pd[4] = {0.f, 0.f, 0.f, 0.f};
  float pn[4] = {0.f, 0.f, 0.f, 0.f};
  #pragma unroll
  for (int n = 0; n < 8; ++n) {
    int i = n * 16 + lrow;
    int cc = i >> 3, ko = i & 7;
    #pragma unroll
    for (int r = 0; r < 4; ++r) {
      int tl = w * 16 + lgrp * 4 + r;
      float v = xs[cc][tl + ko];
      pd[r] = fmaf(acc[n][r], v, pd[r]);
      pn[r] = fmaf(v, v, pn[r]);
    }
  }
  #pragma unroll
  for (int r = 0; r < 4; ++r) {
    #pragma unroll
    for (int m = 1; m < 16; m <<= 1) {
      pd[r] += __shfl_xor(pd[r], m);
      pn[r] += __shfl_xor(pn[r], m);
    }
  }
  if (lrow == 0) {
    #pragma unroll
    for (int r = 0; r < 4; ++r) {
      int t = t0 + w * 16 + lgrp * 4 + r;
      if (t < LOUT) out[(size_t)b * LOUT + t] = pd[r] / (pn[r] + 1e-12f);
    }
  }
}

// ---------------------------------------------------------------------------

extern "C" void kernel_launch(void* const* d_in, const int* in_sizes, int n_in,
                              void* d_out, int out_size, void* d_ws, size_t ws_size,
                              hipStream_t stream) {
  const float* x     = (const float*)d_in[0];   // (16,16,4096) f32
  const float* E     = (const float*)d_in[1];   // (512,512)    f32
  const float* theta = (const float*)d_in[2];   // (3,9)        f32
  float* out = (float*)d_out;                   // (16,1,1,4089) f32
  (void)d_ws; (void)ws_size;

  w1_kernel<<<QDIM, 256, 0, stream>>>(E, theta);                 // -> g_B (W1)
  mm_fused4_kernel<<<QDIM, 512, 0, stream>>>(E, theta, 1, 0);    // g_B -> g_C
  mm_fused4_kernel<<<QDIM, 512, 0, stream>>>(E, theta, 2, 1);    // g_C -> g_B (A)
  formq_kernel<<<DD, 512, 0, stream>>>();                        // g_B -> g_Qh/g_Ql
  quadQ_kernel<<<dim3(NB, 64), 256, 0, stream>>>(x, out);
}

// Round 26
// 47.977 us; speedup vs baseline: 1.4794x; 1.1006x over previous
//
#include <hip/hip_runtime.h>
#include <math.h>

// Problem constants
#define QDIM 512     // 2^9 state dim
#define DD   128     // K*C_IN = input dim of quadratic form
#define LIN  4096
#define LOUT 4089    // (4096 - 7 - 1)/1 + 1
#define NC   16      // C_IN
#define NB   16      // batch

typedef __attribute__((ext_vector_type(8))) short bf16x8;
typedef __attribute__((ext_vector_type(4))) float f32x4;

// Scratch in device globals (NOT d_ws) — R5 lesson. Every element rewritten
// each call before read. R8+R11: no grid barriers. R19: Q-path. R18:
// cooperative LDS staging. R23/R24/R25: latency-bound small kernels ->
// split-K TLP. R26: quadQ m=2 tiles (B-frag reuse x2, staging traffic /2).
__device__ float  g_B[QDIM * DD];          // W1 / A (ping-pong) f32
__device__ float  g_C[QDIM * DD];          // W2 f32
__device__ unsigned short g_Qh[DD * DD];   // bf16 hi part of Q
__device__ unsigned short g_Ql[DD * DD];   // bf16 residual of Q

// ---- bf16 helpers (RNE) ----
__device__ __forceinline__ unsigned short f2bf(float f) {
  union { float f; unsigned u; } v; v.f = f;
  unsigned u = v.u + 0x7FFFu + ((v.u >> 16) & 1u);
  return (unsigned short)(u >> 16);
}
__device__ __forceinline__ float bf2f(unsigned short h) {
  union { unsigned u; float f; } v; v.u = ((unsigned)h) << 16;
  return v.f;
}

// ---------------------------------------------------------------------------
// Precompute. Row i of E*R*W = (R^T e_i)^T W (transposed butterflies,
// reverse qubit order, on the E-row in LDS).
// ---------------------------------------------------------------------------
__device__ __forceinline__ void butterfly_T(float* col, const float* theta,
                                            int l, int p) {
  #pragma unroll
  for (int qq = 0; qq < 9; ++qq) {
    int q = 8 - qq;                    // reverse order for transpose
    float half = theta[l * 9 + q] * 0.5f;
    float c = cosf(half), s = sinf(half);
    int right = QDIM >> (q + 1);
    int a = p >> (8 - q);
    int r = p & (right - 1);
    int i0 = (a * 2) * right + r;
    int i1 = i0 + right;
    float v0 = col[i0], v1 = col[i1];
    col[i0] = c * v0 + s * v1;         // transposed 2x2
    col[i1] = c * v1 - s * v0;
    __syncthreads();
  }
}

// W1[i][j] = (R1^T e_i)[j], j<128  -> g_B   (verbatim R20/R24)
__global__ __launch_bounds__(256) void w1_kernel(const float* __restrict__ E,
                                                 const float* __restrict__ theta) {
  __shared__ float erow[QDIM];
  int i = blockIdx.x;
  int p = threadIdx.x;
  erow[p]       = E[i * QDIM + p];
  erow[p + 256] = E[i * QDIM + p + 256];
  __syncthreads();
  butterfly_T(erow, theta, 0, p);
  if (p < DD) g_B[i * DD + p] = erow[p];
}

// dst[i][:] = (R_l^T e_i)^T * src.  512 blocks x 512 threads (4 K-quarters)
// -> 4 waves/SIMD (verbatim R24, measured-good).
__global__ __launch_bounds__(512) void mm_fused4_kernel(const float* __restrict__ E,
                                                        const float* __restrict__ theta,
                                                        int l, int sel) {
  const float* W = sel ? g_C : g_B;
  float* D       = sel ? g_B : g_C;
  __shared__ float erow[QDIM];
  __shared__ float part[4][DD];
  int i = blockIdx.x;
  int tid = threadIdx.x;                 // 0..511
  erow[tid] = E[i * QDIM + tid];
  __syncthreads();
  // transposed butterflies: 256 worker threads, barriers outside the guard
  #pragma unroll
  for (int qq = 0; qq < 9; ++qq) {
    int q = 8 - qq;
    float half = theta[l * 9 + q] * 0.5f;
    float c = cosf(half), s = sinf(half);
    if (tid < 256) {
      int right = QDIM >> (q + 1);
      int a = tid >> (8 - q);
      int r = tid & (right - 1);
      int x0 = (a * 2) * right + r;
      int x1 = x0 + right;
      float v0 = erow[x0], v1 = erow[x1];
      erow[x0] = c * v0 + s * v1;
      erow[x1] = c * v1 - s * v0;
    }
    __syncthreads();
  }

  int j = tid & 127, qtr = tid >> 7;     // 128 j x 4 K-quarters
  float a0 = 0.f, a1 = 0.f, a2 = 0.f, a3 = 0.f;
  int m0 = qtr * 128;
  #pragma unroll 8
  for (int m = m0; m < m0 + 128; m += 4) {
    a0 = fmaf(erow[m + 0], W[(m + 0) * DD + j], a0);
    a1 = fmaf(erow[m + 1], W[(m + 1) * DD + j], a1);
    a2 = fmaf(erow[m + 2], W[(m + 2) * DD + j], a2);
    a3 = fmaf(erow[m + 3], W[(m + 3) * DD + j], a3);
  }
  part[qtr][j] = (a0 + a1) + (a2 + a3);
  __syncthreads();
  if (tid < DD) {
    D[i * DD + tid] = (part[0][tid] + part[1][tid]) +
                      (part[2][tid] + part[3][tid]);
  }
}

// Q[j1][j2] = sum_i sgn(i) A[i][j1] A[i][j2]; A = g_B. Emit bf16 hi/lo.
// (verbatim R25: 512 threads, split-K x4)
__global__ __launch_bounds__(512) void formq_kernel() {
  const float* A = g_B;
  __shared__ float colA[QDIM];
  __shared__ float part[4][DD];
  int j1 = blockIdx.x;
  int tid = threadIdx.x;                 // 0..511
  int j2 = tid & 127, qtr = tid >> 7;    // 128 j2 x 4 i-quarters
  {
    float sgn = (tid < 256) ? 1.0f : -1.0f;
    colA[tid] = sgn * A[tid * DD + j1];
  }
  __syncthreads();
  float a0 = 0.f, a1 = 0.f, a2 = 0.f, a3 = 0.f;
  int i0 = qtr * 128;
  #pragma unroll 8
  for (int i = i0; i < i0 + 128; i += 4) {
    a0 = fmaf(colA[i + 0], A[(i + 0) * DD + j2], a0);
    a1 = fmaf(colA[i + 1], A[(i + 1) * DD + j2], a1);
    a2 = fmaf(colA[i + 2], A[(i + 2) * DD + j2], a2);
    a3 = fmaf(colA[i + 3], A[(i + 3) * DD + j2], a3);
  }
  part[qtr][j2] = (a0 + a1) + (a2 + a3);
  __syncthreads();
  if (tid < DD) {
    float sum = (part[0][tid] + part[1][tid]) +
                (part[2][tid] + part[3][tid]);
    unsigned short hi = f2bf(sum);
    unsigned short lo = f2bf(sum - bf2f(hi));
    g_Qh[j1 * DD + tid] = hi;
    g_Ql[j1 * DD + tid] = lo;
  }
}

// ---------------------------------------------------------------------------
// quadQ v2: t-tile = 128 (512 blocks, 2/CU resident, 3/CU capacity).
// Wave w covers 2 m-tiles of 16 t-rows; B-frags (Qh LDS + Ql L2) shared
// across both m-tiles -> 2x MFMA per operand read; Qh staging chip-wide
// traffic halved. Per-t MFMA order identical to R20/R25 -> absmax canary
// 4.882812e-4.
// ---------------------------------------------------------------------------
__global__ __launch_bounds__(256, 3) void quadQ_kernel(const float* __restrict__ x,
                                                       float* __restrict__ out) {
  __shared__ float xs[NC][136];                // 135 used (128 t + 7 halo)
  __shared__ unsigned short sh_full[DD * DD];  // Qh, 32 KB, swizzled
  int b = blockIdx.x;
  int t0 = blockIdx.y * 128;
  int tid = threadIdx.x;
  int lane = tid & 63;
  int w = tid >> 6;                            // wave: t-rows [w*32, w*32+32)
  const float* xb = x + (size_t)b * NC * LIN;

  for (int idx = tid; idx < NC * 135; idx += 256) {
    int c = idx / 135, o = idx % 135;
    int g = t0 + o;
    xs[c][o] = (g < LIN) ? xb[c * LIN + g] : 0.0f;
  }
  // stage Qh (2048 granules of 8 u16), XOR swizzle: u16col ^= (row&7)<<3
  #pragma unroll
  for (int it = 0; it < 8; ++it) {
    int flat = it * 256 + tid;
    int row = flat >> 4;                       // 0..127
    int g8 = flat & 15;
    int lidx = row * DD + ((g8 * 8) ^ ((row & 7) << 3));
    *(bf16x8*)&sh_full[lidx] = *(const bf16x8*)(g_Qh + row * DD + g8 * 8);
  }
  __syncthreads();

  int lrow = lane & 15;
  int lgrp = lane >> 4;

  f32x4 acc[2][8];
  #pragma unroll
  for (int m = 0; m < 2; ++m)
    #pragma unroll
    for (int n = 0; n < 8; ++n) acc[m][n] = (f32x4){0.f, 0.f, 0.f, 0.f};

  #pragma unroll
  for (int kb = 0; kb < 4; ++kb) {
    int c = kb * 4 + lgrp;
    bf16x8 a_hi[2], a_lo[2];
    #pragma unroll
    for (int m = 0; m < 2; ++m) {
      int tl = w * 32 + m * 16 + lrow;
      #pragma unroll
      for (int e = 0; e < 8; ++e) {
        float v = xs[c][tl + e];
        unsigned short hh = f2bf(v);
        unsigned short ll = f2bf(v - bf2f(hh));
        a_hi[m][e] = (short)hh;
        a_lo[m][e] = (short)ll;
      }
    }
    #pragma unroll
    for (int n = 0; n < 8; ++n) {
      int row = n * 16 + lrow;
      int col = kb * 32 + lgrp * 8;
      bf16x8 b_hi = *(const bf16x8*)&sh_full[row * DD + (col ^ ((row & 7) << 3))];
      bf16x8 b_lo = *(const bf16x8*)(g_Ql + row * DD + col);
      #pragma unroll
      for (int m = 0; m < 2; ++m) {
        acc[m][n] = __builtin_amdgcn_mfma_f32_16x16x32_bf16(a_hi[m], b_hi, acc[m][n], 0, 0, 0);
        acc[m][n] = __builtin_amdgcn_mfma_f32_16x16x32_bf16(a_hi[m], b_lo, acc[m][n], 0, 0, 0);
        acc[m][n] = __builtin_amdgcn_mfma_f32_16x16x32_bf16(a_lo[m], b_hi, acc[m][n], 0, 0, 0);
      }
    }
  }

  // Epilogue: dot with v and ||v||^2, 16-lane reduce (per m-tile).
  float pd[2][4] = {{0.f,0.f,0.f,0.f},{0.f,0.f,0.f,0.f}};
  float pn[2][4] = {{0.f,0.f,0.f,0.f},{0.f,0.f,0.f,0.f}};
  #pragma unroll
  for (int n = 0; n < 8; ++n) {
    int i = n * 16 + lrow;
    int cc = i >> 3, ko = i & 7;
    #pragma unroll
    for (int m = 0; m < 2; ++m) {
      #pragma unroll
      for (int r = 0; r < 4; ++r) {
        int tl = w * 32 + m * 16 + lgrp * 4 + r;
        float v = xs[cc][tl + ko];
        pd[m][r] = fmaf(acc[m][n][r], v, pd[m][r]);
        pn[m][r] = fmaf(v, v, pn[m][r]);
      }
    }
  }
  #pragma unroll
  for (int m = 0; m < 2; ++m)
    #pragma unroll
    for (int r = 0; r < 4; ++r) {
      #pragma unroll
      for (int msk = 1; msk < 16; msk <<= 1) {
        pd[m][r] += __shfl_xor(pd[m][r], msk);
        pn[m][r] += __shfl_xor(pn[m][r], msk);
      }
    }
  if (lrow == 0) {
    #pragma unroll
    for (int m = 0; m < 2; ++m)
      #pragma unroll
      for (int r = 0; r < 4; ++r) {
        int t = t0 + w * 32 + m * 16 + lgrp * 4 + r;
        if (t < LOUT) out[(size_t)b * LOUT + t] = pd[m][r] / (pn[m][r] + 1e-12f);
      }
  }
}

// ---------------------------------------------------------------------------

extern "C" void kernel_launch(void* const* d_in, const int* in_sizes, int n_in,
                              void* d_out, int out_size, void* d_ws, size_t ws_size,
                              hipStream_t stream) {
  const float* x     = (const float*)d_in[0];   // (16,16,4096) f32
  const float* E     = (const float*)d_in[1];   // (512,512)    f32
  const float* theta = (const float*)d_in[2];   // (3,9)        f32
  float* out = (float*)d_out;                   // (16,1,1,4089) f32
  (void)d_ws; (void)ws_size;

  w1_kernel<<<QDIM, 256, 0, stream>>>(E, theta);                 // -> g_B (W1)
  mm_fused4_kernel<<<QDIM, 512, 0, stream>>>(E, theta, 1, 0);    // g_B -> g_C
  mm_fused4_kernel<<<QDIM, 512, 0, stream>>>(E, theta, 2, 1);    // g_C -> g_B (A)
  formq_kernel<<<DD, 512, 0, stream>>>();                        // g_B -> g_Qh/g_Ql
  quadQ_kernel<<<dim3(NB, 32), 256, 0, stream>>>(x, out);
}